// Round 12
// baseline (55.463 us; speedup 1.0000x reference)
//
#include <hip/hip_runtime.h>

#define NS 8192
#define MS 2048
#define DD 32
#define MSPLIT 32
#define MCH (MS / MSPLIT)     // 64 m per block
#define NITS (MCH / 16)       // 4 m-tiles

typedef __attribute__((ext_vector_type(8))) short bf16x8;
typedef __attribute__((ext_vector_type(4))) float f32x4;
typedef unsigned short u16;
typedef unsigned int u32;

// ws byte offsets
#define PART_OFF 0                          // [MSPLIT][NS] f32 (1 MB)
#define DIST_OFF (MSPLIT * NS * 4)          // [NS] f32
#define MM_OFF   (DIST_OFF + NS * 4)        // 2 u32 (min,max bits)
#define CNT_OFF  (MM_OFF + 8)               // 1 u32

__device__ inline float fast_exp2(float x) {
#if __has_builtin(__builtin_amdgcn_exp2f)
    return __builtin_amdgcn_exp2f(x);
#else
    return exp2f(x);
#endif
}

// 2x f32 -> packed bf16 pair, RNE, one instruction (no builtin on gfx950).
__device__ inline u32 cvt_pk_bf16(float a, float b) {
    u32 r;
    asm("v_cvt_pk_bf16_f32 %0, %1, %2" : "=v"(r) : "v"(a), "v"(b));
    return r;
}

// Split 8 floats into hi/lo bf16x8. Pack-order of cvt_pk is irrelevant to
// correctness: X and W use the same helper, so the MFMA dot pairs identical
// k-elements either way.
__device__ inline void split8(const float* v, bf16x8& hi, bf16x8& lo) {
    union { u32 u[4]; bf16x8 b; } H, L;
#pragma unroll
    for (int j = 0; j < 4; ++j) {
        u32 h = cvt_pk_bf16(v[2 * j], v[2 * j + 1]);
        float ha = __uint_as_float(h << 16);            // bf2f(low half)
        float hb = __uint_as_float(h & 0xFFFF0000u);    // bf2f(high half)
        L.u[j] = cvt_pk_bf16(v[2 * j] - ha, v[2 * j + 1] - hb);
        H.u[j] = h;
    }
    hi = H.b;
    lo = L.b;
}

// Fused main (R11 body, unchanged). This round it is launched 4x IDENTICALLY
// as a diagnostic: each launch writes the same deterministic values (idempotent),
// so correctness is unaffected, and rocprof finally reports this kernel's
// duration + counters directly (it has never cracked the top-5 past the
// harness's 39us poison-fill dispatches).
__global__ __launch_bounds__(256, 4) void kde_fused(const float* __restrict__ samples,
                                                    const float* __restrict__ means,
                                                    const float* __restrict__ stds,
                                                    unsigned char* __restrict__ wsb) {
    __shared__ u16 WBH[NITS * 4 * 16 * 8];   // [it][g][r15][8]
    __shared__ u16 WBL[NITS * 4 * 16 * 8];
    __shared__ u16 WCH[NITS * 4 * 16 * 8];
    __shared__ u16 WCL[NITS * 4 * 16 * 8];
    __shared__ float A2s[MCH];

    const int t = threadIdx.x;
    const int m0 = blockIdx.y * MCH;
    const float L2E = 1.4426950408889634f;

    if (blockIdx.x == 0 && blockIdx.y == 0 && t == 0) {
        unsigned* mm = (unsigned*)(wsb + MM_OFF);
        mm[0] = 0x7f7fffffu;  // FLT_MAX bits (uint cmp == float cmp for positives)
        mm[1] = 0u;
        *(unsigned*)(wsb + CNT_OFF) = 0u;
    }

    // ---- phase 1: W chunk -> LDS, one thread per (m_local, 8-d quarter) ----
    {
        const int ml = t >> 2, qd = t & 3;
        const float* mp = means + (size_t)(m0 + ml) * DD + qd * 8;
        const float* vp = stds  + (size_t)(m0 + ml) * DD + qd * 8;
        float4 a4 = *(const float4*)mp, b4 = *(const float4*)(mp + 4);
        float4 c4 = *(const float4*)vp, d4 = *(const float4*)(vp + 4);
        float mu[8] = {a4.x, a4.y, a4.z, a4.w, b4.x, b4.y, b4.z, b4.w};
        float sd[8] = {c4.x, c4.y, c4.z, c4.w, d4.x, d4.y, d4.z, d4.w};
        float Bv[8], Cv[8], a = 0.f;
#pragma unroll
        for (int j = 0; j < 8; ++j) {
            float inv = 1.0f / sd[j];
            Bv[j] = L2E * mu[j] * inv;
            Cv[j] = -0.5f * L2E * inv;
            a += mu[j] * mu[j] * inv;
        }
        a += __shfl_xor(a, 1);
        a += __shfl_xor(a, 2);
        if (qd == 0) A2s[ml] = -0.5f * L2E * a - 11.0f;  // -log2(M) folds the mean

        bf16x8 bh, bl, ch, cl;
        split8(Bv, bh, bl);
        split8(Cv, ch, cl);
        const int it = ml >> 4, r15 = ml & 15;
        const int base = ((it * 4 + qd) * 16 + r15) * 8;
        *(bf16x8*)&WBH[base] = bh;
        *(bf16x8*)&WBL[base] = bl;
        *(bf16x8*)&WCH[base] = ch;
        *(bf16x8*)&WCL[base] = cl;
    }

    // ---- phase 2: X fragments straight from samples ----
    const int lane = t & 63, wid = t >> 6;
    const int r15 = lane & 15, g = lane >> 4;
    const int n0 = blockIdx.x * 256 + wid * 64;

    bf16x8 xh[4], xl[4], qh[4], ql[4];
#pragma unroll
    for (int nt = 0; nt < 4; ++nt) {
        const float* sp = samples + (size_t)(n0 + nt * 16 + r15) * DD + g * 8;
        float4 a4 = *(const float4*)sp, b4 = *(const float4*)(sp + 4);
        float xv[8] = {a4.x, a4.y, a4.z, a4.w, b4.x, b4.y, b4.z, b4.w};
        float qv[8];
#pragma unroll
        for (int j = 0; j < 8; ++j) qv[j] = xv[j] * xv[j];
        split8(xv, xh[nt], xl[nt]);
        split8(qv, qh[nt], ql[nt]);
    }

    __syncthreads();

    // ---- phase 3: m-loop over LDS-resident W, dual-accumulator tiles ----
    f32x4 rs[4];
#pragma unroll
    for (int nt = 0; nt < 4; ++nt) rs[nt] = (f32x4){0.f, 0.f, 0.f, 0.f};

#pragma unroll 2
    for (int it = 0; it < NITS; ++it) {
        const int base = ((it * 4 + g) * 16 + r15) * 8;
        bf16x8 bh = *(const bf16x8*)&WBH[base];
        bf16x8 ch = *(const bf16x8*)&WCH[base];
        bf16x8 bl = *(const bf16x8*)&WBL[base];
        bf16x8 cl = *(const bf16x8*)&WCL[base];
        const float a2 = A2s[it * 16 + r15];
#pragma unroll
        for (int nt = 0; nt < 4; ++nt) {
            f32x4 accB = (f32x4){0.f, 0.f, 0.f, 0.f};
            f32x4 accC = (f32x4){0.f, 0.f, 0.f, 0.f};
            accB = __builtin_amdgcn_mfma_f32_16x16x32_bf16(xh[nt], bh, accB, 0, 0, 0);
            accC = __builtin_amdgcn_mfma_f32_16x16x32_bf16(qh[nt], ch, accC, 0, 0, 0);
            accB = __builtin_amdgcn_mfma_f32_16x16x32_bf16(xl[nt], bh, accB, 0, 0, 0);
            accC = __builtin_amdgcn_mfma_f32_16x16x32_bf16(ql[nt], ch, accC, 0, 0, 0);
            accB = __builtin_amdgcn_mfma_f32_16x16x32_bf16(xh[nt], bl, accB, 0, 0, 0);
            accC = __builtin_amdgcn_mfma_f32_16x16x32_bf16(qh[nt], cl, accC, 0, 0, 0);
#pragma unroll
            for (int r = 0; r < 4; ++r)
                rs[nt][r] += fast_exp2((accB[r] + accC[r]) + a2);
        }
    }

    // sum the 16 m-columns (lanes sharing g)
#pragma unroll
    for (int o = 1; o < 16; o <<= 1)
#pragma unroll
        for (int nt = 0; nt < 4; ++nt)
#pragma unroll
            for (int r = 0; r < 4; ++r) rs[nt][r] += __shfl_xor(rs[nt][r], o);

    float* partial = (float*)(wsb + PART_OFF);
    if (r15 == 0) {
#pragma unroll
        for (int nt = 0; nt < 4; ++nt)
            *(f32x4*)(partial + (size_t)blockIdx.y * NS + n0 + nt * 16 + g * 4) = rs[nt];
    }
}

// Sum partials -> dist, block min/max -> atomics; last block finalizes out.
__global__ __launch_bounds__(256) void reduce_final(unsigned char* __restrict__ ws,
                                                    float* __restrict__ out) {
    const float* partial = (const float*)(ws + PART_OFF);
    float* dist = (float*)(ws + DIST_OFF);
    unsigned* mm = (unsigned*)(ws + MM_OFF);
    unsigned* cnt = (unsigned*)(ws + CNT_OFF);

    const int tid = threadIdx.x;
    const int n = blockIdx.x * 256 + tid;
    float v = 0.f;
#pragma unroll
    for (int j = 0; j < MSPLIT; ++j) v += partial[(size_t)j * NS + n];
    dist[n] = v;

    float mn = v, mx = v;
#pragma unroll
    for (int o = 1; o < 64; o <<= 1) {
        mn = fminf(mn, __shfl_xor(mn, o));
        mx = fmaxf(mx, __shfl_xor(mx, o));
    }
    __shared__ float smn[4], smx[4];
    __shared__ int lastFlag;
    const int wv = tid >> 6, ln = tid & 63;
    if (ln == 0) { smn[wv] = mn; smx[wv] = mx; }
    __syncthreads();
    if (tid == 0) {
#pragma unroll
        for (int j = 1; j < 4; ++j) {
            mn = fminf(mn, smn[j]);
            mx = fmaxf(mx, smx[j]);
        }
        atomicMin(mm + 0, __float_as_uint(mn));
        atomicMax(mm + 1, __float_as_uint(mx));
        __threadfence();
        unsigned old = atomicAdd(cnt, 1u);
        lastFlag = (old == (unsigned)(gridDim.x - 1));
    }
    __syncthreads();
    if (lastFlag) {
        __threadfence();
        volatile unsigned* vmm = mm;
        const float fmn = __uint_as_float(vmm[0]);
        const float fmx = __uint_as_float(vmm[1]);
        volatile float* vd = dist;
        for (int i = tid; i < NS; i += 256) out[i] = fmx + fmn - vd[i];
    }
}

extern "C" void kernel_launch(void* const* d_in, const int* in_sizes, int n_in,
                              void* d_out, int out_size, void* d_ws, size_t ws_size,
                              hipStream_t stream) {
    const float* samples = (const float*)d_in[0];
    const float* means   = (const float*)d_in[1];
    const float* stds    = (const float*)d_in[2];
    unsigned char* ws = (unsigned char*)d_ws;
    float* out = (float*)d_out;

    // DIAGNOSTIC (this round only): 4 identical, idempotent launches so the
    // main kernel appears in rocprof's top-5 with true duration + counters.
    // Launches 2-4 rewrite the exact same values; output is unchanged.
    for (int rep = 0; rep < 4; ++rep)
        kde_fused<<<dim3(NS / 256, MSPLIT), 256, 0, stream>>>(samples, means, stds, ws);
    reduce_final<<<dim3(NS / 256), 256, 0, stream>>>(ws, out);
}

// Round 13
// 19.469 us; speedup vs baseline: 2.8488x; 2.8488x over previous
//
#include <hip/hip_runtime.h>

#define NS 8192
#define MS 2048
#define DD 32
#define MSPLIT 32
#define MCH (MS / MSPLIT)     // 64 m per block
#define NITS (MCH / 16)       // 4 m-tiles

typedef __attribute__((ext_vector_type(8))) short bf16x8;
typedef __attribute__((ext_vector_type(4))) float f32x4;
typedef unsigned short u16;
typedef unsigned int u32;

// ws byte offsets
#define PART_OFF 0                          // [MSPLIT][NS] f32 (1 MB)
#define DIST_OFF (MSPLIT * NS * 4)          // [NS] f32
#define MM_OFF   (DIST_OFF + NS * 4)        // 2 u32 (min,max bits)

__device__ inline float fast_exp2(float x) {
#if __has_builtin(__builtin_amdgcn_exp2f)
    return __builtin_amdgcn_exp2f(x);
#else
    return exp2f(x);
#endif
}

// 2x f32 -> packed bf16 pair, RNE, one instruction (no builtin on gfx950).
__device__ inline u32 cvt_pk_bf16(float a, float b) {
    u32 r;
    asm("v_cvt_pk_bf16_f32 %0, %1, %2" : "=v"(r) : "v"(a), "v"(b));
    return r;
}

// Split 8 floats into hi/lo bf16x8. Pack-order of cvt_pk is irrelevant to
// correctness: X and W use the same helper, so the MFMA dot pairs identical
// k-elements either way.
__device__ inline void split8(const float* v, bf16x8& hi, bf16x8& lo) {
    union { u32 u[4]; bf16x8 b; } H, L;
#pragma unroll
    for (int j = 0; j < 4; ++j) {
        u32 h = cvt_pk_bf16(v[2 * j], v[2 * j + 1]);
        float ha = __uint_as_float(h << 16);            // bf2f(low half)
        float hb = __uint_as_float(h & 0xFFFF0000u);    // bf2f(high half)
        L.u[j] = cvt_pk_bf16(v[2 * j] - ha, v[2 * j + 1] - hb);
        H.u[j] = h;
    }
    hi = H.b;
    lo = L.b;
}

// Fused main (R11 body; counter init dropped). Block (0,0) re-inits the
// min/max slots every call; kernel-boundary release makes them visible to
// reduce_mm's atomics.
__global__ __launch_bounds__(256, 4) void kde_fused(const float* __restrict__ samples,
                                                    const float* __restrict__ means,
                                                    const float* __restrict__ stds,
                                                    unsigned char* __restrict__ wsb) {
    __shared__ u16 WBH[NITS * 4 * 16 * 8];   // [it][g][r15][8]
    __shared__ u16 WBL[NITS * 4 * 16 * 8];
    __shared__ u16 WCH[NITS * 4 * 16 * 8];
    __shared__ u16 WCL[NITS * 4 * 16 * 8];
    __shared__ float A2s[MCH];

    const int t = threadIdx.x;
    const int m0 = blockIdx.y * MCH;
    const float L2E = 1.4426950408889634f;

    if (blockIdx.x == 0 && blockIdx.y == 0 && t == 0) {
        unsigned* mm = (unsigned*)(wsb + MM_OFF);
        mm[0] = 0x7f7fffffu;  // FLT_MAX bits (uint cmp == float cmp for positives)
        mm[1] = 0u;
    }

    // ---- phase 1: W chunk -> LDS, one thread per (m_local, 8-d quarter) ----
    {
        const int ml = t >> 2, qd = t & 3;
        const float* mp = means + (size_t)(m0 + ml) * DD + qd * 8;
        const float* vp = stds  + (size_t)(m0 + ml) * DD + qd * 8;
        float4 a4 = *(const float4*)mp, b4 = *(const float4*)(mp + 4);
        float4 c4 = *(const float4*)vp, d4 = *(const float4*)(vp + 4);
        float mu[8] = {a4.x, a4.y, a4.z, a4.w, b4.x, b4.y, b4.z, b4.w};
        float sd[8] = {c4.x, c4.y, c4.z, c4.w, d4.x, d4.y, d4.z, d4.w};
        float Bv[8], Cv[8], a = 0.f;
#pragma unroll
        for (int j = 0; j < 8; ++j) {
            float inv = 1.0f / sd[j];
            Bv[j] = L2E * mu[j] * inv;
            Cv[j] = -0.5f * L2E * inv;
            a += mu[j] * mu[j] * inv;
        }
        a += __shfl_xor(a, 1);
        a += __shfl_xor(a, 2);
        if (qd == 0) A2s[ml] = -0.5f * L2E * a - 11.0f;  // -log2(M) folds the mean

        bf16x8 bh, bl, ch, cl;
        split8(Bv, bh, bl);
        split8(Cv, ch, cl);
        const int it = ml >> 4, r15 = ml & 15;
        const int base = ((it * 4 + qd) * 16 + r15) * 8;
        *(bf16x8*)&WBH[base] = bh;
        *(bf16x8*)&WBL[base] = bl;
        *(bf16x8*)&WCH[base] = ch;
        *(bf16x8*)&WCL[base] = cl;
    }

    // ---- phase 2: X fragments straight from samples ----
    const int lane = t & 63, wid = t >> 6;
    const int r15 = lane & 15, g = lane >> 4;
    const int n0 = blockIdx.x * 256 + wid * 64;

    bf16x8 xh[4], xl[4], qh[4], ql[4];
#pragma unroll
    for (int nt = 0; nt < 4; ++nt) {
        const float* sp = samples + (size_t)(n0 + nt * 16 + r15) * DD + g * 8;
        float4 a4 = *(const float4*)sp, b4 = *(const float4*)(sp + 4);
        float xv[8] = {a4.x, a4.y, a4.z, a4.w, b4.x, b4.y, b4.z, b4.w};
        float qv[8];
#pragma unroll
        for (int j = 0; j < 8; ++j) qv[j] = xv[j] * xv[j];
        split8(xv, xh[nt], xl[nt]);
        split8(qv, qh[nt], ql[nt]);
    }

    __syncthreads();

    // ---- phase 3: m-loop over LDS-resident W, dual-accumulator tiles ----
    f32x4 rs[4];
#pragma unroll
    for (int nt = 0; nt < 4; ++nt) rs[nt] = (f32x4){0.f, 0.f, 0.f, 0.f};

#pragma unroll 2
    for (int it = 0; it < NITS; ++it) {
        const int base = ((it * 4 + g) * 16 + r15) * 8;
        bf16x8 bh = *(const bf16x8*)&WBH[base];
        bf16x8 ch = *(const bf16x8*)&WCH[base];
        bf16x8 bl = *(const bf16x8*)&WBL[base];
        bf16x8 cl = *(const bf16x8*)&WCL[base];
        const float a2 = A2s[it * 16 + r15];
#pragma unroll
        for (int nt = 0; nt < 4; ++nt) {
            f32x4 accB = (f32x4){0.f, 0.f, 0.f, 0.f};
            f32x4 accC = (f32x4){0.f, 0.f, 0.f, 0.f};
            accB = __builtin_amdgcn_mfma_f32_16x16x32_bf16(xh[nt], bh, accB, 0, 0, 0);
            accC = __builtin_amdgcn_mfma_f32_16x16x32_bf16(qh[nt], ch, accC, 0, 0, 0);
            accB = __builtin_amdgcn_mfma_f32_16x16x32_bf16(xl[nt], bh, accB, 0, 0, 0);
            accC = __builtin_amdgcn_mfma_f32_16x16x32_bf16(ql[nt], ch, accC, 0, 0, 0);
            accB = __builtin_amdgcn_mfma_f32_16x16x32_bf16(xh[nt], bl, accB, 0, 0, 0);
            accC = __builtin_amdgcn_mfma_f32_16x16x32_bf16(qh[nt], cl, accC, 0, 0, 0);
#pragma unroll
            for (int r = 0; r < 4; ++r)
                rs[nt][r] += fast_exp2((accB[r] + accC[r]) + a2);
        }
    }

    // sum the 16 m-columns (lanes sharing g)
#pragma unroll
    for (int o = 1; o < 16; o <<= 1)
#pragma unroll
        for (int nt = 0; nt < 4; ++nt)
#pragma unroll
            for (int r = 0; r < 4; ++r) rs[nt][r] += __shfl_xor(rs[nt][r], o);

    float* partial = (float*)(wsb + PART_OFF);
    if (r15 == 0) {
#pragma unroll
        for (int nt = 0; nt < 4; ++nt)
            *(f32x4*)(partial + (size_t)blockIdx.y * NS + n0 + nt * 16 + g * 4) = rs[nt];
    }
}

// dist[n] = sum_j partial[j][n]; block min/max -> 2 atomics per block.
// No counter, no volatile, no spin — the old last-block pattern cost ~8us
// in serialized volatile loads + skew (R12 probe: reduce_final ~13us).
__global__ __launch_bounds__(256) void reduce_mm(const unsigned char* __restrict__ wsb,
                                                 float* __restrict__ dist,
                                                 unsigned* __restrict__ mm) {
    const float* partial = (const float*)(wsb + PART_OFF);
    const int tid = threadIdx.x;
    const int n = blockIdx.x * 256 + tid;
    float v = 0.f;
#pragma unroll
    for (int j = 0; j < MSPLIT; ++j) v += partial[(size_t)j * NS + n];
    dist[n] = v;

    float mn = v, mx = v;
#pragma unroll
    for (int o = 1; o < 64; o <<= 1) {
        mn = fminf(mn, __shfl_xor(mn, o));
        mx = fmaxf(mx, __shfl_xor(mx, o));
    }
    __shared__ float smn[4], smx[4];
    const int wv = tid >> 6, ln = tid & 63;
    if (ln == 0) { smn[wv] = mn; smx[wv] = mx; }
    __syncthreads();
    if (tid == 0) {
#pragma unroll
        for (int j = 1; j < 4; ++j) {
            mn = fminf(mn, smn[j]);
            mx = fmaxf(mx, smx[j]);
        }
        atomicMin(mm + 0, __float_as_uint(mn));
        atomicMax(mm + 1, __float_as_uint(mx));
    }
}

// out[n] = max + min - dist[n], fully parallel, vectorized.
__global__ __launch_bounds__(256) void finalize(const float* __restrict__ dist,
                                                const unsigned* __restrict__ mm,
                                                float* __restrict__ out) {
    const int i = blockIdx.x * 256 + threadIdx.x;   // f32x4 index
    const float fmn = __uint_as_float(mm[0]);
    const float fmx = __uint_as_float(mm[1]);
    f32x4 d = ((const f32x4*)dist)[i];
    f32x4 o;
#pragma unroll
    for (int r = 0; r < 4; ++r) o[r] = fmx + fmn - d[r];
    ((f32x4*)out)[i] = o;
}

extern "C" void kernel_launch(void* const* d_in, const int* in_sizes, int n_in,
                              void* d_out, int out_size, void* d_ws, size_t ws_size,
                              hipStream_t stream) {
    const float* samples = (const float*)d_in[0];
    const float* means   = (const float*)d_in[1];
    const float* stds    = (const float*)d_in[2];
    unsigned char* ws = (unsigned char*)d_ws;
    float* out = (float*)d_out;

    float* dist = (float*)(ws + DIST_OFF);
    unsigned* mm = (unsigned*)(ws + MM_OFF);

    kde_fused<<<dim3(NS / 256, MSPLIT), 256, 0, stream>>>(samples, means, stds, ws);
    reduce_mm<<<dim3(NS / 256), 256, 0, stream>>>(ws, dist, mm);
    finalize<<<dim3(NS / 4 / 256), 256, 0, stream>>>(dist, mm, out);
}